// Round 2
// baseline (833.055 us; speedup 1.0000x reference)
//
#include <hip/hip_runtime.h>
#include <math.h>

#define NBR    4        // NUM_BRANCHES
#define REP    1024     // REP_DIM
#define FD     128      // FEAT_DIM
#define NDATA  100000
#define KP1    4097     // NCE_K + 1
#define BN     128      // BATCH
#define MPN    0.04096f // m * Pn = 4096 / 100000
#define EPS_C  1e-7f
#define TINV   (1.0f / 0.07f)
#define KS     16       // k-split for pass kernels (j-major dispatch)

// ---------------------------------------------------------------------------
// bf16 pack/unpack (RNE)
// ---------------------------------------------------------------------------
static __device__ __forceinline__ unsigned short f2bf(float f) {
    union { float f; unsigned int u; } c; c.f = f;
    unsigned int u = c.u;
    u += 0x7fffu + ((u >> 16) & 1u);   // round to nearest even
    return (unsigned short)(u >> 16);
}
static __device__ __forceinline__ float bf2f(unsigned short h) {
    union { unsigned int u; float f; } c; c.u = ((unsigned int)h) << 16;
    return c.f;
}

// ---------------------------------------------------------------------------
// Kernel 1: h[r,b,d] = sum_i emb_r[b,i] * W[r,d,i] + bias[r,d];  e = h/||h||
// grid (NBR, BN), block 128 (one thread per d)
// ---------------------------------------------------------------------------
__global__ void k_feat(const float* __restrict__ e0, const float* __restrict__ e1,
                       const float* __restrict__ e2, const float* __restrict__ e3,
                       const float* __restrict__ W, const float* __restrict__ bias,
                       float* __restrict__ e_out) {
    const int r = blockIdx.x;
    const int b = blockIdx.y;
    const float* emb = (r == 0 ? e0 : r == 1 ? e1 : r == 2 ? e2 : e3) + (size_t)b * REP;

    __shared__ float s_emb[REP];
    for (int i = threadIdx.x; i < REP; i += blockDim.x) s_emb[i] = emb[i];
    __syncthreads();

    const int d = threadIdx.x;  // 0..127
    const float4* wrow = (const float4*)(W + ((size_t)r * FD + d) * REP);
    float acc = 0.f;
#pragma unroll 8
    for (int c = 0; c < REP / 4; ++c) {
        float4 v = wrow[c];
        acc += v.x * s_emb[4*c+0] + v.y * s_emb[4*c+1]
             + v.z * s_emb[4*c+2] + v.w * s_emb[4*c+3];
    }
    float h = acc + bias[r * FD + d];

    __shared__ float red[FD];
    red[d] = h * h;
    __syncthreads();
    for (int off = FD / 2; off > 0; off >>= 1) {
        if (d < off) red[d] += red[d + off];
        __syncthreads();
    }
    float nrm = sqrtf(red[0]);
    e_out[((size_t)r * BN + b) * FD + d] = h / nrm;
}

// ---------------------------------------------------------------------------
// Per-row 4-way dot: row (float4*, 128 floats) vs s_e[i*FD + :] for i=0..3
// LDS reads are wave-uniform (broadcast) -> conflict-free.
// ---------------------------------------------------------------------------
static __device__ __forceinline__ void dot4(const float4* __restrict__ row,
                                            const float* __restrict__ se,
                                            float& a0, float& a1, float& a2, float& a3) {
    a0 = a1 = a2 = a3 = 0.f;
#pragma unroll 8
    for (int c = 0; c < FD / 4; ++c) {
        float4 v = row[c];
        const int o = 4 * c;
        a0 += v.x * se[0*FD+o+0] + v.y * se[0*FD+o+1] + v.z * se[0*FD+o+2] + v.w * se[0*FD+o+3];
        a1 += v.x * se[1*FD+o+0] + v.y * se[1*FD+o+1] + v.z * se[1*FD+o+2] + v.w * se[1*FD+o+3];
        a2 += v.x * se[2*FD+o+0] + v.y * se[2*FD+o+1] + v.z * se[2*FD+o+2] + v.w * se[2*FD+o+3];
        a3 += v.x * se[3*FD+o+0] + v.y * se[3*FD+o+1] + v.z * se[3*FD+o+2] + v.w * se[3*FD+o+3];
    }
}

// ---------------------------------------------------------------------------
// Epilogue term:
//   pos (k==0):  log(pos/(pos+c))  = -log1p(c/pos),        c = MPN+EPS
//   neg (k>=1):  log(MPN/(neg+c))  = -log1p((neg+EPS)/MPN)
// fast-log form: log1p(x) = __logf(1+x)
// ---------------------------------------------------------------------------
static __device__ __forceinline__ float term_of(float ex, float zinv, int k) {
    const float c = MPN + EPS_C;
    float v = ex * zinv;
    if (k == 0) return -__logf(1.0f + c / v);
    return -__logf(1.0f + (v + EPS_C) * (1.0f / MPN));
}

// ---------------------------------------------------------------------------
// Pass 1: for each (j,b,k): row = memory[j, cidx[b,k], :]
//         s_i = dot(row, e[i,b,:]);  ex_i = exp(s_i/T)
//         Zsum[i][j] += ex_i;  optionally store ex as bf16x4 at [j][b][k]
// grid (KS, BN, NBR)  -- j SLOWEST so the resident-block window stays inside
// one 51 MB memory[j] slice (L3-resident re-reads). block 256.
// ---------------------------------------------------------------------------
template <bool STORE>
__global__ void k_pass1(const float* __restrict__ e, const float* __restrict__ memory,
                        const int* __restrict__ cidx,
                        float* __restrict__ Zsum, ushort4* __restrict__ expS) {
    const int j = blockIdx.z;
    const int b = blockIdx.y;

    __shared__ float s_e[NBR * FD];
    for (int t = threadIdx.x; t < NBR * FD; t += blockDim.x) {
        int i = t >> 7, d = t & (FD - 1);
        s_e[t] = e[((size_t)i * BN + b) * FD + d];
    }
    __syncthreads();

    const int* ci = cidx + (size_t)b * KP1;
    const float4* mem4 = (const float4*)(memory + (size_t)j * NDATA * FD);
    float z0 = 0.f, z1 = 0.f, z2 = 0.f, z3 = 0.f;

    for (int k = threadIdx.x + blockIdx.x * blockDim.x; k < KP1;
         k += blockDim.x * gridDim.x) {
        const int n = ci[k];
        const float4* row = mem4 + (size_t)n * (FD / 4);
        float a0, a1, a2, a3;
        dot4(row, s_e, a0, a1, a2, a3);
        float x0 = __expf(a0 * TINV);
        float x1 = __expf(a1 * TINV);
        float x2 = __expf(a2 * TINV);
        float x3 = __expf(a3 * TINV);
        z0 += x0; z1 += x1; z2 += x2; z3 += x3;
        if (STORE) {
            ushort4 st;
            st.x = f2bf(x0); st.y = f2bf(x1); st.z = f2bf(x2); st.w = f2bf(x3);
            expS[((size_t)j * BN + b) * KP1 + k] = st;
        }
    }

    __shared__ float sred[256];
    float zs[NBR] = {z0, z1, z2, z3};
    for (int i = 0; i < NBR; ++i) {
        sred[threadIdx.x] = zs[i];
        __syncthreads();
        for (int off = 128; off > 0; off >>= 1) {
            if ((int)threadIdx.x < off) sred[threadIdx.x] += sred[threadIdx.x + off];
            __syncthreads();
        }
        if (threadIdx.x == 0) atomicAdd(&Zsum[i * NBR + j], sred[0]);
        __syncthreads();
    }
}

// ---------------------------------------------------------------------------
// Pass 2 (stored path): stream bf16 expS back, accumulate per-(i,j) term sums
// grid (4, BN, NBR), block 256
// ---------------------------------------------------------------------------
__global__ void k_pass2_stored(const ushort4* __restrict__ expS,
                               const float* __restrict__ Zsum,
                               float* __restrict__ accum) {
    const int j = blockIdx.z;
    const int b = blockIdx.y;

    __shared__ float s_zinv[NBR];
    if (threadIdx.x < NBR) {
        float Z = Zsum[threadIdx.x * NBR + j] *
                  (float)((double)NDATA / ((double)BN * (double)KP1));
        s_zinv[threadIdx.x] = 1.0f / Z;
    }
    __syncthreads();

    const ushort4* es = expS + ((size_t)j * BN + b) * KP1;
    float a0 = 0.f, a1 = 0.f, a2 = 0.f, a3 = 0.f;

    for (int k = threadIdx.x + blockIdx.x * blockDim.x; k < KP1;
         k += blockDim.x * gridDim.x) {
        ushort4 v = es[k];
        a0 += term_of(bf2f(v.x), s_zinv[0], k);
        a1 += term_of(bf2f(v.y), s_zinv[1], k);
        a2 += term_of(bf2f(v.z), s_zinv[2], k);
        a3 += term_of(bf2f(v.w), s_zinv[3], k);
    }

    __shared__ float sred[256];
    float as[NBR] = {a0, a1, a2, a3};
    for (int i = 0; i < NBR; ++i) {
        sred[threadIdx.x] = as[i];
        __syncthreads();
        for (int off = 128; off > 0; off >>= 1) {
            if ((int)threadIdx.x < off) sred[threadIdx.x] += sred[threadIdx.x + off];
            __syncthreads();
        }
        if (threadIdx.x == 0) atomicAdd(&accum[i * NBR + j], sred[0]);
        __syncthreads();
    }
}

// ---------------------------------------------------------------------------
// Pass 2 (fallback, re-gather): recompute dots, j-localized like pass1
// grid (KS, BN, NBR), block 256
// ---------------------------------------------------------------------------
__global__ void k_pass2_regather(const float* __restrict__ e, const float* __restrict__ memory,
                                 const int* __restrict__ cidx,
                                 const float* __restrict__ Zsum, float* __restrict__ accum) {
    const int j = blockIdx.z;
    const int b = blockIdx.y;

    __shared__ float s_e[NBR * FD];
    __shared__ float s_zinv[NBR];
    for (int t = threadIdx.x; t < NBR * FD; t += blockDim.x) {
        int i = t >> 7, d = t & (FD - 1);
        s_e[t] = e[((size_t)i * BN + b) * FD + d];
    }
    if (threadIdx.x < NBR) {
        float Z = Zsum[threadIdx.x * NBR + j] *
                  (float)((double)NDATA / ((double)BN * (double)KP1));
        s_zinv[threadIdx.x] = 1.0f / Z;
    }
    __syncthreads();

    const int* ci = cidx + (size_t)b * KP1;
    const float4* mem4 = (const float4*)(memory + (size_t)j * NDATA * FD);
    float a0s = 0.f, a1s = 0.f, a2s = 0.f, a3s = 0.f;

    for (int k = threadIdx.x + blockIdx.x * blockDim.x; k < KP1;
         k += blockDim.x * gridDim.x) {
        const int n = ci[k];
        const float4* row = mem4 + (size_t)n * (FD / 4);
        float a0, a1, a2, a3;
        dot4(row, s_e, a0, a1, a2, a3);
        a0s += term_of(__expf(a0 * TINV), s_zinv[0], k);
        a1s += term_of(__expf(a1 * TINV), s_zinv[1], k);
        a2s += term_of(__expf(a2 * TINV), s_zinv[2], k);
        a3s += term_of(__expf(a3 * TINV), s_zinv[3], k);
    }

    __shared__ float sred[256];
    float as[NBR] = {a0s, a1s, a2s, a3s};
    for (int i = 0; i < NBR; ++i) {
        sred[threadIdx.x] = as[i];
        __syncthreads();
        for (int off = 128; off > 0; off >>= 1) {
            if ((int)threadIdx.x < off) sred[threadIdx.x] += sred[threadIdx.x + off];
            __syncthreads();
        }
        if (threadIdx.x == 0) atomicAdd(&accum[i * NBR + j], sred[0]);
        __syncthreads();
    }
}

// ---------------------------------------------------------------------------
__global__ void k_init(float* __restrict__ p) {
    if (threadIdx.x < 32) p[threadIdx.x] = 0.f;  // Zsum[16] + accum[16]
}

__global__ void k_final(const float* __restrict__ accum, float* __restrict__ out) {
    if (threadIdx.x == 0) {
        float s = 0.f;
        for (int i = 0; i < NBR; ++i)
            for (int j = 0; j < NBR; ++j)
                if (i != j) s += -accum[i * NBR + j] / (float)BN;
        out[0] = s;
    }
}

// ---------------------------------------------------------------------------
extern "C" void kernel_launch(void* const* d_in, const int* in_sizes, int n_in,
                              void* d_out, int out_size, void* d_ws, size_t ws_size,
                              hipStream_t stream) {
    const float* e0   = (const float*)d_in[0];
    const float* e1   = (const float*)d_in[1];
    const float* e2   = (const float*)d_in[2];
    const float* e3   = (const float*)d_in[3];
    const float* W    = (const float*)d_in[4];
    const float* bias = (const float*)d_in[5];
    const float* mem  = (const float*)d_in[6];
    // d_in[7] = idx (unused; contrast_idx[:,0] == idx)
    const int*   cidx = (const int*)d_in[8];
    float* out = (float*)d_out;

    float* ws    = (float*)d_ws;
    float* e     = ws;            // 4*128*128 = 65536 floats (256 KB)
    float* Zsum  = ws + 65536;    // 16 floats
    float* accum = ws + 65552;    // 16 floats
    ushort4* expS = (ushort4*)(ws + 65568);  // byte offset 262272 (16B aligned)

    const size_t need_bytes =
        (size_t)65568 * 4 + (size_t)NBR * BN * KP1 * sizeof(ushort4); // ~17 MB
    const bool store = ws_size >= need_bytes;

    k_init<<<1, 64, 0, stream>>>(Zsum);
    k_feat<<<dim3(NBR, BN), 128, 0, stream>>>(e0, e1, e2, e3, W, bias, e);

    dim3 grid(KS, BN, NBR);   // x fastest => all of j=0 dispatches before j=1
    if (store) {
        k_pass1<true><<<grid, 256, 0, stream>>>(e, mem, cidx, Zsum, expS);
        k_pass2_stored<<<dim3(4, BN, NBR), 256, 0, stream>>>(expS, Zsum, accum);
    } else {
        k_pass1<false><<<grid, 256, 0, stream>>>(e, mem, cidx, Zsum, nullptr);
        k_pass2_regather<<<grid, 256, 0, stream>>>(e, mem, cidx, Zsum, accum);
    }
    k_final<<<1, 64, 0, stream>>>(accum, out);
}

// Round 4
// 590.343 us; speedup vs baseline: 1.4111x; 1.4111x over previous
//
#include <hip/hip_runtime.h>
#include <math.h>

#define NBR    4        // NUM_BRANCHES
#define REP    1024     // REP_DIM
#define FD     128      // FEAT_DIM
#define NDATA  100000
#define KP1    4097     // NCE_K + 1
#define BN     128      // BATCH
#define MPN    0.04096f // m * Pn = 4096 / 100000
#define EPS_C  1e-7f
#define TINV   (1.0f / 0.07f)

typedef unsigned int uint4e __attribute__((ext_vector_type(4)));
typedef unsigned short ushort4e __attribute__((ext_vector_type(4)));

// ---------------------------------------------------------------------------
// bf16 helpers (RNE), operating on raw bits
// ---------------------------------------------------------------------------
static __device__ __forceinline__ unsigned short bfbits(unsigned int u) {
    u += 0x7fffu + ((u >> 16) & 1u);
    return (unsigned short)(u >> 16);
}
static __device__ __forceinline__ unsigned short f2bf(float f) {
    union { float f; unsigned int u; } c; c.f = f;
    return bfbits(c.u);
}
static __device__ __forceinline__ float bf2f(unsigned short h) {
    union { unsigned int u; float f; } c; c.u = ((unsigned int)h) << 16;
    return c.f;
}
static __device__ __forceinline__ float lo_of(unsigned int u) {
    union { unsigned int u; float f; } c; c.u = u << 16; return c.f;
}
static __device__ __forceinline__ float hi_of(unsigned int u) {
    union { unsigned int u; float f; } c; c.u = u & 0xffff0000u; return c.f;
}

// ---------------------------------------------------------------------------
// Kernel: memory fp32 -> bf16 (bits) into workspace. Non-temporal reads so the
// dead fp32 copy doesn't pollute L3 (bf16 copy + expS must stay L3-resident).
// Uses clang ext_vector_type (HIP uint4 is rejected by the builtin).
// ---------------------------------------------------------------------------
__global__ void k_convert(const uint4e* __restrict__ src, ushort4e* __restrict__ dst,
                          int n4) {
    int i = blockIdx.x * blockDim.x + threadIdx.x;
    const int stride = gridDim.x * blockDim.x;
    for (; i < n4; i += stride) {
        uint4e v = __builtin_nontemporal_load(&src[i]);
        ushort4e o;
        o.x = bfbits(v.x); o.y = bfbits(v.y); o.z = bfbits(v.z); o.w = bfbits(v.w);
        dst[i] = o;
    }
}

// ---------------------------------------------------------------------------
// Kernel: h[r,b,d] = sum_i emb_r[b,i] * W[r,d,i] + bias;  e = h/||h||
// grid (NBR, BN), block 128
// ---------------------------------------------------------------------------
__global__ void k_feat(const float* __restrict__ e0, const float* __restrict__ e1,
                       const float* __restrict__ e2, const float* __restrict__ e3,
                       const float* __restrict__ W, const float* __restrict__ bias,
                       float* __restrict__ e_out) {
    const int r = blockIdx.x;
    const int b = blockIdx.y;
    const float* emb = (r == 0 ? e0 : r == 1 ? e1 : r == 2 ? e2 : e3) + (size_t)b * REP;

    __shared__ float s_emb[REP];
    for (int i = threadIdx.x; i < REP; i += blockDim.x) s_emb[i] = emb[i];
    __syncthreads();

    const int d = threadIdx.x;
    const float4* wrow = (const float4*)(W + ((size_t)r * FD + d) * REP);
    float acc = 0.f;
#pragma unroll 8
    for (int c = 0; c < REP / 4; ++c) {
        float4 v = wrow[c];
        acc += v.x * s_emb[4*c+0] + v.y * s_emb[4*c+1]
             + v.z * s_emb[4*c+2] + v.w * s_emb[4*c+3];
    }
    float h = acc + bias[r * FD + d];

    __shared__ float red[FD];
    red[d] = h * h;
    __syncthreads();
    for (int off = FD / 2; off > 0; off >>= 1) {
        if (d < off) red[d] += red[d + off];
        __syncthreads();
    }
    float nrm = sqrtf(red[0]);
    e_out[((size_t)r * BN + b) * FD + d] = h / nrm;
}

// ---------------------------------------------------------------------------
// Block reduce 4 partials + atomicAdd into dst[i*NBR+j]
// ---------------------------------------------------------------------------
static __device__ __forceinline__ void block_reduce4(float z0, float z1, float z2,
                                                     float z3, float* dst, int j) {
    __shared__ float sred[256];
    float zs[NBR] = {z0, z1, z2, z3};
    for (int i = 0; i < NBR; ++i) {
        sred[threadIdx.x] = zs[i];
        __syncthreads();
        for (int off = 128; off > 0; off >>= 1) {
            if ((int)threadIdx.x < off) sred[threadIdx.x] += sred[threadIdx.x + off];
            __syncthreads();
        }
        if (threadIdx.x == 0) atomicAdd(&dst[i * NBR + j], sred[0]);
        __syncthreads();
    }
}

// ---------------------------------------------------------------------------
// Pass 1 (bf16 memory): grid (4, BN, NBR) -- j slowest (L3 locality).
// Each thread gathers 4 rows concurrently (k = base + r*1024), 16 loads in
// flight per chunk, LDS e-broadcast shared across the 4 rows.
// ---------------------------------------------------------------------------
__global__ __launch_bounds__(256)
void k_pass1_bf16(const float* __restrict__ e, const ushort* __restrict__ memb,
                  const int* __restrict__ cidx,
                  float* __restrict__ Zsum, ushort4* __restrict__ expS) {
    const int j = blockIdx.z;
    const int b = blockIdx.y;

    __shared__ float s_e[NBR * FD];
    for (int t = threadIdx.x; t < NBR * FD; t += 256) {
        int i = t >> 7, d = t & (FD - 1);
        s_e[t] = e[((size_t)i * BN + b) * FD + d];
    }
    __syncthreads();

    const int* ci = cidx + (size_t)b * KP1;
    const uint4* mb = (const uint4*)(memb + (size_t)j * NDATA * FD); // 16 uint4 / row
    const int base = threadIdx.x + blockIdx.x * 256;   // [0, 1024)

    const uint4* rp[4];
#pragma unroll
    for (int r = 0; r < 4; ++r) {
        int n = ci[base + r * 1024];
        rp[r] = mb + (size_t)n * 16;
    }

    float a[4][NBR];
#pragma unroll
    for (int r = 0; r < 4; ++r)
#pragma unroll
        for (int i = 0; i < NBR; ++i) a[r][i] = 0.f;

    // 16 uint4 per row, processed in 4 chunks of 4 (16 loads in flight / chunk)
#pragma unroll
    for (int c = 0; c < 16; c += 4) {
        uint4 d[4][4];
#pragma unroll
        for (int r = 0; r < 4; ++r)
#pragma unroll
            for (int cc = 0; cc < 4; ++cc) d[r][cc] = rp[r][c + cc];

#pragma unroll
        for (int cc = 0; cc < 4; ++cc) {
#pragma unroll
            for (int q = 0; q < 4; ++q) {
                const int o = (c + cc) * 8 + q * 2;
                unsigned int u0 = (&d[0][cc].x)[q];
                unsigned int u1 = (&d[1][cc].x)[q];
                unsigned int u2 = (&d[2][cc].x)[q];
                unsigned int u3 = (&d[3][cc].x)[q];
#pragma unroll
                for (int i = 0; i < NBR; ++i) {
                    const float sl = s_e[i * FD + o];
                    const float sh = s_e[i * FD + o + 1];
                    a[0][i] += lo_of(u0) * sl + hi_of(u0) * sh;
                    a[1][i] += lo_of(u1) * sl + hi_of(u1) * sh;
                    a[2][i] += lo_of(u2) * sl + hi_of(u2) * sh;
                    a[3][i] += lo_of(u3) * sl + hi_of(u3) * sh;
                }
            }
        }
    }

    float z0 = 0.f, z1 = 0.f, z2 = 0.f, z3 = 0.f;
    ushort4* es = expS + ((size_t)j * BN + b) * KP1;
#pragma unroll
    for (int r = 0; r < 4; ++r) {
        float x0 = __expf(a[r][0] * TINV);
        float x1 = __expf(a[r][1] * TINV);
        float x2 = __expf(a[r][2] * TINV);
        float x3 = __expf(a[r][3] * TINV);
        z0 += x0; z1 += x1; z2 += x2; z3 += x3;
        ushort4 st; st.x = f2bf(x0); st.y = f2bf(x1); st.z = f2bf(x2); st.w = f2bf(x3);
        es[base + r * 1024] = st;
    }

    // tail k = 4096 (one thread per (j,b))
    if (base == 0) {
        int n = ci[4096];
        const uint4* rt = mb + (size_t)n * 16;
        float t0 = 0.f, t1 = 0.f, t2 = 0.f, t3 = 0.f;
#pragma unroll
        for (int c = 0; c < 16; ++c) {
            uint4 v = rt[c];
#pragma unroll
            for (int q = 0; q < 4; ++q) {
                unsigned int u = (&v.x)[q];
                const int o = c * 8 + q * 2;
                float f0 = lo_of(u), f1 = hi_of(u);
                t0 += f0 * s_e[0*FD+o] + f1 * s_e[0*FD+o+1];
                t1 += f0 * s_e[1*FD+o] + f1 * s_e[1*FD+o+1];
                t2 += f0 * s_e[2*FD+o] + f1 * s_e[2*FD+o+1];
                t3 += f0 * s_e[3*FD+o] + f1 * s_e[3*FD+o+1];
            }
        }
        float x0 = __expf(t0 * TINV), x1 = __expf(t1 * TINV);
        float x2 = __expf(t2 * TINV), x3 = __expf(t3 * TINV);
        z0 += x0; z1 += x1; z2 += x2; z3 += x3;
        ushort4 st; st.x = f2bf(x0); st.y = f2bf(x1); st.z = f2bf(x2); st.w = f2bf(x3);
        es[4096] = st;
    }

    block_reduce4(z0, z1, z2, z3, Zsum, j);
}

// ---------------------------------------------------------------------------
// fp32 4-way dot (fallback paths)
// ---------------------------------------------------------------------------
static __device__ __forceinline__ void dot4(const float4* __restrict__ row,
                                            const float* __restrict__ se,
                                            float& a0, float& a1, float& a2, float& a3) {
    a0 = a1 = a2 = a3 = 0.f;
#pragma unroll 8
    for (int c = 0; c < FD / 4; ++c) {
        float4 v = row[c];
        const int o = 4 * c;
        a0 += v.x * se[0*FD+o+0] + v.y * se[0*FD+o+1] + v.z * se[0*FD+o+2] + v.w * se[0*FD+o+3];
        a1 += v.x * se[1*FD+o+0] + v.y * se[1*FD+o+1] + v.z * se[1*FD+o+2] + v.w * se[1*FD+o+3];
        a2 += v.x * se[2*FD+o+0] + v.y * se[2*FD+o+1] + v.z * se[2*FD+o+2] + v.w * se[2*FD+o+3];
        a3 += v.x * se[3*FD+o+0] + v.y * se[3*FD+o+1] + v.z * se[3*FD+o+2] + v.w * se[3*FD+o+3];
    }
}

// ---------------------------------------------------------------------------
// Pass 1 (fp32 fallback): grid (4, BN, NBR) j-slowest, stride loop (4-5 rows/thread)
// ---------------------------------------------------------------------------
template <bool STORE>
__global__ void k_pass1_f32(const float* __restrict__ e, const float* __restrict__ memory,
                            const int* __restrict__ cidx,
                            float* __restrict__ Zsum, ushort4* __restrict__ expS) {
    const int j = blockIdx.z;
    const int b = blockIdx.y;

    __shared__ float s_e[NBR * FD];
    for (int t = threadIdx.x; t < NBR * FD; t += blockDim.x) {
        int i = t >> 7, d = t & (FD - 1);
        s_e[t] = e[((size_t)i * BN + b) * FD + d];
    }
    __syncthreads();

    const int* ci = cidx + (size_t)b * KP1;
    const float4* mem4 = (const float4*)(memory + (size_t)j * NDATA * FD);
    float z0 = 0.f, z1 = 0.f, z2 = 0.f, z3 = 0.f;

    for (int k = threadIdx.x + blockIdx.x * blockDim.x; k < KP1;
         k += blockDim.x * gridDim.x) {
        const int n = ci[k];
        const float4* row = mem4 + (size_t)n * (FD / 4);
        float a0, a1, a2, a3;
        dot4(row, s_e, a0, a1, a2, a3);
        float x0 = __expf(a0 * TINV);
        float x1 = __expf(a1 * TINV);
        float x2 = __expf(a2 * TINV);
        float x3 = __expf(a3 * TINV);
        z0 += x0; z1 += x1; z2 += x2; z3 += x3;
        if (STORE) {
            ushort4 st;
            st.x = f2bf(x0); st.y = f2bf(x1); st.z = f2bf(x2); st.w = f2bf(x3);
            expS[((size_t)j * BN + b) * KP1 + k] = st;
        }
    }
    block_reduce4(z0, z1, z2, z3, Zsum, j);
}

// ---------------------------------------------------------------------------
// Epilogue term:
//   pos (k==0):  -log1p(c/pos),          c = MPN+EPS
//   neg (k>=1):  -log1p((neg+EPS)/MPN)
// ---------------------------------------------------------------------------
static __device__ __forceinline__ float term_of(float ex, float zinv, int k) {
    const float c = MPN + EPS_C;
    float v = ex * zinv;
    if (k == 0) return -__logf(1.0f + c / v);
    return -__logf(1.0f + (v + EPS_C) * (1.0f / MPN));
}

__global__ void k_pass2_stored(const ushort4* __restrict__ expS,
                               const float* __restrict__ Zsum,
                               float* __restrict__ accum) {
    const int j = blockIdx.z;
    const int b = blockIdx.y;

    __shared__ float s_zinv[NBR];
    if (threadIdx.x < NBR) {
        float Z = Zsum[threadIdx.x * NBR + j] *
                  (float)((double)NDATA / ((double)BN * (double)KP1));
        s_zinv[threadIdx.x] = 1.0f / Z;
    }
    __syncthreads();

    const ushort4* es = expS + ((size_t)j * BN + b) * KP1;
    float a0 = 0.f, a1 = 0.f, a2 = 0.f, a3 = 0.f;

    for (int k = threadIdx.x + blockIdx.x * blockDim.x; k < KP1;
         k += blockDim.x * gridDim.x) {
        ushort4 v = es[k];
        a0 += term_of(bf2f(v.x), s_zinv[0], k);
        a1 += term_of(bf2f(v.y), s_zinv[1], k);
        a2 += term_of(bf2f(v.z), s_zinv[2], k);
        a3 += term_of(bf2f(v.w), s_zinv[3], k);
    }
    block_reduce4(a0, a1, a2, a3, accum, j);
}

__global__ void k_pass2_regather(const float* __restrict__ e, const float* __restrict__ memory,
                                 const int* __restrict__ cidx,
                                 const float* __restrict__ Zsum, float* __restrict__ accum) {
    const int j = blockIdx.z;
    const int b = blockIdx.y;

    __shared__ float s_e[NBR * FD];
    __shared__ float s_zinv[NBR];
    for (int t = threadIdx.x; t < NBR * FD; t += blockDim.x) {
        int i = t >> 7, d = t & (FD - 1);
        s_e[t] = e[((size_t)i * BN + b) * FD + d];
    }
    if (threadIdx.x < NBR) {
        float Z = Zsum[threadIdx.x * NBR + j] *
                  (float)((double)NDATA / ((double)BN * (double)KP1));
        s_zinv[threadIdx.x] = 1.0f / Z;
    }
    __syncthreads();

    const int* ci = cidx + (size_t)b * KP1;
    const float4* mem4 = (const float4*)(memory + (size_t)j * NDATA * FD);
    float a0s = 0.f, a1s = 0.f, a2s = 0.f, a3s = 0.f;

    for (int k = threadIdx.x + blockIdx.x * blockDim.x; k < KP1;
         k += blockDim.x * gridDim.x) {
        const int n = ci[k];
        const float4* row = mem4 + (size_t)n * (FD / 4);
        float a0, a1, a2, a3;
        dot4(row, s_e, a0, a1, a2, a3);
        a0s += term_of(__expf(a0 * TINV), s_zinv[0], k);
        a1s += term_of(__expf(a1 * TINV), s_zinv[1], k);
        a2s += term_of(__expf(a2 * TINV), s_zinv[2], k);
        a3s += term_of(__expf(a3 * TINV), s_zinv[3], k);
    }
    block_reduce4(a0s, a1s, a2s, a3s, accum, j);
}

// ---------------------------------------------------------------------------
__global__ void k_init(float* __restrict__ p) {
    if (threadIdx.x < 32) p[threadIdx.x] = 0.f;  // Zsum[16] + accum[16]
}

__global__ void k_final(const float* __restrict__ accum, float* __restrict__ out) {
    if (threadIdx.x == 0) {
        float s = 0.f;
        for (int i = 0; i < NBR; ++i)
            for (int j = 0; j < NBR; ++j)
                if (i != j) s += -accum[i * NBR + j] / (float)BN;
        out[0] = s;
    }
}

// ---------------------------------------------------------------------------
extern "C" void kernel_launch(void* const* d_in, const int* in_sizes, int n_in,
                              void* d_out, int out_size, void* d_ws, size_t ws_size,
                              hipStream_t stream) {
    const float* e0   = (const float*)d_in[0];
    const float* e1   = (const float*)d_in[1];
    const float* e2   = (const float*)d_in[2];
    const float* e3   = (const float*)d_in[3];
    const float* W    = (const float*)d_in[4];
    const float* bias = (const float*)d_in[5];
    const float* mem  = (const float*)d_in[6];
    const int*   cidx = (const int*)d_in[8];
    float* out = (float*)d_out;

    // workspace layout (floats): e[65536] | Zsum[16] | accum[16] | ...
    float* ws    = (float*)d_ws;
    float* e     = ws;
    float* Zsum  = ws + 65536;
    float* accum = ws + 65552;
    const size_t base_b   = (size_t)65568 * 4;               // 262272 B (16-aligned)
    const size_t membf_b  = (size_t)NBR * NDATA * FD * 2;    // 102,400,000 B
    const size_t expS_b   = (size_t)NBR * BN * KP1 * 8;      // 16,781,312 B

    ushort* membf = (ushort*)((char*)d_ws + base_b);

    const size_t need_full = base_b + membf_b + expS_b;      // ~119.4 MB
    const size_t need_mid  = base_b + expS_b;                // ~17.0 MB

    k_init<<<1, 64, 0, stream>>>(Zsum);
    k_feat<<<dim3(NBR, BN), 128, 0, stream>>>(e0, e1, e2, e3, W, bias, e);

    if (ws_size >= need_full) {
        ushort4* expS = (ushort4*)((char*)d_ws + base_b + membf_b);
        const int n4 = NBR * NDATA * FD / 4;                 // 12.8M uint4
        k_convert<<<2048, 256, 0, stream>>>((const uint4e*)mem, (ushort4e*)membf, n4);
        k_pass1_bf16<<<dim3(4, BN, NBR), 256, 0, stream>>>(e, membf, cidx, Zsum, expS);
        k_pass2_stored<<<dim3(4, BN, NBR), 256, 0, stream>>>(expS, Zsum, accum);
    } else if (ws_size >= need_mid) {
        ushort4* expS = (ushort4*)((char*)d_ws + base_b);
        k_pass1_f32<true><<<dim3(4, BN, NBR), 256, 0, stream>>>(e, mem, cidx, Zsum, expS);
        k_pass2_stored<<<dim3(4, BN, NBR), 256, 0, stream>>>(expS, Zsum, accum);
    } else {
        k_pass1_f32<false><<<dim3(4, BN, NBR), 256, 0, stream>>>(e, mem, cidx, Zsum, nullptr);
        k_pass2_regather<<<dim3(4, BN, NBR), 256, 0, stream>>>(e, mem, cidx, Zsum, accum);
    }
    k_final<<<1, 64, 0, stream>>>(accum, out);
}